// Round 6
// baseline (1721.393 us; speedup 1.0000x reference)
//
#include <hip/hip_runtime.h>

#define DEV static __device__ __forceinline__

namespace {
constexpr int D     = 256;
constexpr int SALL  = 22;
constexpr int NAC   = 20;
constexpr int NWIN  = 7;
constexpr int NB    = 32;
constexpr int NF    = 16;
constexpr int SPF   = 192;   // 8*24 spatial per frame
constexpr int NTOK  = 768;   // 4*SPF
constexpr int BWIN  = 224;   // NWIN*NB
constexpr int PARTS = 8;     // pass1 blocks per window (224*8 = 1792 = 7*256 -> perfect CU balance)
constexpr int TPP   = 3;     // tiles (of 32 tokens) per part; 24 tiles total
constexpr float LNEPS = 1e-5f;
constexpr float EPS   = 1e-8f;
constexpr float SCL   = 0.0625f;  // 256^-0.5

// workspace layout (float offsets)
constexpr int OFF_PE   = 0;                        // [768][256]
constexpr int OFF_FC1T = OFF_PE   + 768 * 256;     // [256][256] (k-major transposes)
constexpr int OFF_FC2T = OFF_FC1T + 256 * 256;
constexpr int OFF_VWT  = OFF_FC2T + 256 * 256;
constexpr int OFF_QWT  = OFF_VWT  + 256 * 256;
constexpr int OFF_FF1T = OFF_QWT  + 256 * 256;
constexpr int OFF_FF2T = OFF_FF1T + 256 * 256;
constexpr int OFF_GWIT = OFF_FF2T + 256 * 256;     // [256][768]
constexpr int OFF_GWHT = OFF_GWIT + 256 * 768;     // [256][768]
constexpr int OFF_Q    = OFF_GWHT + 256 * 768;     // [22][256]
constexpr int OFF_QK2T = OFF_Q    + SALL * 256;    // [256][22]
constexpr int OFF_QB   = OFF_QK2T + 256 * SALL;    // [32]
constexpr int OFF_HG0  = OFF_QB   + 32;            // [22][768]
constexpr int OFF_UPDP = OFF_HG0  + SALL * 768;    // [1792][20][256]
constexpr int OFF_RSP  = OFF_UPDP + BWIN * PARTS * NAC * 256; // [1792][20]
} // namespace

DEV float4 ld4(const float* p) { return *(const float4*)p; }
DEV float sigm(float x) { return 1.f / (1.f + __expf(-x)); }

// ---------------------------------------------------------------- transposes
struct TPtrs {
    const float* src[8];
    float*       dst[8];
    int          osz[8];
};

__global__ void k_trans(TPtrs p) {
    __shared__ float t[32][33];
    const int bt = blockIdx.x;
    int m, tile;
    if (bt < 384) { m = bt >> 6; tile = bt & 63; }
    else          { m = 6 + (bt - 384) / 192; tile = (bt - 384) % 192; }
    const int O  = p.osz[m];
    const int rt = O >> 5;
    const int o0 = (tile % rt) * 32, i0 = (tile / rt) * 32;
    const int tx = threadIdx.x & 31, ty = threadIdx.x >> 5;
    const float* src = p.src[m];
    float*       dst = p.dst[m];
#pragma unroll
    for (int q = 0; q < 4; ++q) { int r = ty + q * 8; t[r][tx] = src[(o0 + r) * 256 + i0 + tx]; }
    __syncthreads();
#pragma unroll
    for (int q = 0; q < 4; ++q) { int r = ty + q * 8; dst[(i0 + r) * O + o0 + tx] = t[tx][r]; }
}

// ---------------------------------------------------------------- pe table
__global__ void k_pe(const float* __restrict__ pw, const float* __restrict__ pb,
                     float* __restrict__ pe) {
    const int p = blockIdx.x;                  // 0..767
    const int fo = p / SPF, rem = p % SPF, hh = rem / 24, ww = rem % 24;
    const float g0 = fo * (1.f / 3.f), g1 = hh * (1.f / 7.f), g2 = ww * (1.f / 23.f);
    const float gg[6] = {g0, g1, g2, 1.f - g0, 1.f - g1, 1.f - g2};
    for (int d = threadIdx.x; d < 256; d += 64) {
        float acc = pb[d];
#pragma unroll
        for (int c = 0; c < 6; ++c) acc = fmaf(gg[c], pw[d * 6 + c], acc);
        pe[p * 256 + d] = acc;
    }
}

// ---------------------------------------------------------------- q = LN_ns(slots) @ qwT + qb ; qbdot = q . k_b
__global__ void k_q(const float* __restrict__ slots, const float* __restrict__ nsg,
                    const float* __restrict__ nsb, const float* __restrict__ qwT,
                    const float* __restrict__ qbias, const float* __restrict__ kb,
                    float* __restrict__ qout, float* __restrict__ qbout) {
    __shared__ float lnb[256];
    __shared__ float red[8];
    const int i = blockIdx.x, t = threadIdx.x, lane = t & 63, wvi = t >> 6;
    const float v = slots[i * 256 + t];
    float s1 = v, s2 = v * v;
#pragma unroll
    for (int m = 32; m; m >>= 1) { s1 += __shfl_xor(s1, m); s2 += __shfl_xor(s2, m); }
    if (lane == 0) { red[wvi] = s1; red[4 + wvi] = s2; }
    __syncthreads();
    const float fs = red[0] + red[1] + red[2] + red[3];
    const float fq = red[4] + red[5] + red[6] + red[7];
    const float mean = fs * (1.f / 256.f);
    const float var  = fq * (1.f / 256.f) - mean * mean;
    const float rstd = rsqrtf(var + LNEPS);
    lnb[t] = (v - mean) * rstd * nsg[t] + nsb[t];
    __syncthreads();
    float qv = qbias[t];
    for (int k = 0; k < 256; ++k) qv = fmaf(lnb[k], qwT[k * 256 + t], qv);
    qout[i * 256 + t] = qv;
    // qb[i] = q[i] . k_b
    float pp = qv * kb[t];
#pragma unroll
    for (int m = 32; m; m >>= 1) pp += __shfl_xor(pp, m);
    __syncthreads();
    if (lane == 0) red[wvi] = pp;
    __syncthreads();
    if (t == 0) qbout[i] = red[0] + red[1] + red[2] + red[3];
}

// ---------------------------------------------------------------- qk2T[k][i] = sum_c q[i][c] * k_w[c][k]
__global__ void k_qk2(const float* __restrict__ qin, const float* __restrict__ kw,
                      float* __restrict__ qk2T) {
    __shared__ float qr[256];
    const int i = blockIdx.x, t = threadIdx.x;
    qr[t] = qin[i * 256 + t];
    __syncthreads();
    float acc = 0.f;
    for (int c = 0; c < 256; ++c) acc = fmaf(qr[c], kw[c * 256 + t], acc);
    qk2T[t * SALL + i] = acc;
}

// ---------------------------------------------------------------- hg0[i][o] = slots[i] @ gwhT + gbh
__global__ void k_hg(const float* __restrict__ slots, const float* __restrict__ gwhT,
                     const float* __restrict__ gbh, float* __restrict__ hg0) {
    __shared__ float sr[256];
    const int i = blockIdx.x, t = threadIdx.x;
    sr[t] = slots[i * 256 + t];
    __syncthreads();
    float a0 = gbh[t], a1 = gbh[t + 256], a2 = gbh[t + 512];
    for (int k = 0; k < 256; ++k) {
        const float s = sr[k];
        a0 = fmaf(s, gwhT[k * 768 + t], a0);
        a1 = fmaf(s, gwhT[k * 768 + t + 256], a1);
        a2 = fmaf(s, gwhT[k * 768 + t + 512], a2);
    }
    hg0[i * 768 + t] = a0;
    hg0[i * 768 + t + 256] = a1;
    hg0[i * 768 + t + 512] = a2;
}

// ---------------------------------------------------------------- pass-1 GEMM step
// 32 tokens x 256 dims; thread = (lane -> 4 cols, wave -> 8 tokens)
// MODE 0: +relu; MODE 1: +LN(ni); MODE 2: plain
template <int MODE>
DEV void gemm_step(const float* __restrict__ srcL, float* __restrict__ dstL,
                   const float4* __restrict__ wT, const float4 bias,
                   const int lane, const int wv, const float4 gni, const float4 bni) {
    float acc[8][4];
#pragma unroll
    for (int j = 0; j < 8; ++j) {
        acc[j][0] = bias.x; acc[j][1] = bias.y; acc[j][2] = bias.z; acc[j][3] = bias.w;
    }
    const float* sp = srcL + (wv << 3) * 256;
    for (int k = 0; k < 256; k += 4) {
        const float4 w0 = wT[((k + 0) << 6) + lane];
        const float4 w1 = wT[((k + 1) << 6) + lane];
        const float4 w2 = wT[((k + 2) << 6) + lane];
        const float4 w3 = wT[((k + 3) << 6) + lane];
#pragma unroll
        for (int j = 0; j < 8; ++j) {
            const float4 x4 = *(const float4*)(sp + j * 256 + k);  // LDS broadcast b128
            acc[j][0] = fmaf(x4.x, w0.x, acc[j][0]);
            acc[j][1] = fmaf(x4.x, w0.y, acc[j][1]);
            acc[j][2] = fmaf(x4.x, w0.z, acc[j][2]);
            acc[j][3] = fmaf(x4.x, w0.w, acc[j][3]);
            acc[j][0] = fmaf(x4.y, w1.x, acc[j][0]);
            acc[j][1] = fmaf(x4.y, w1.y, acc[j][1]);
            acc[j][2] = fmaf(x4.y, w1.z, acc[j][2]);
            acc[j][3] = fmaf(x4.y, w1.w, acc[j][3]);
            acc[j][0] = fmaf(x4.z, w2.x, acc[j][0]);
            acc[j][1] = fmaf(x4.z, w2.y, acc[j][1]);
            acc[j][2] = fmaf(x4.z, w2.z, acc[j][2]);
            acc[j][3] = fmaf(x4.z, w2.w, acc[j][3]);
            acc[j][0] = fmaf(x4.w, w3.x, acc[j][0]);
            acc[j][1] = fmaf(x4.w, w3.y, acc[j][1]);
            acc[j][2] = fmaf(x4.w, w3.z, acc[j][2]);
            acc[j][3] = fmaf(x4.w, w3.w, acc[j][3]);
        }
    }
#pragma unroll
    for (int j = 0; j < 8; ++j) {
        float4 o = {acc[j][0], acc[j][1], acc[j][2], acc[j][3]};
        if constexpr (MODE == 0) {
            o.x = fmaxf(o.x, 0.f); o.y = fmaxf(o.y, 0.f);
            o.z = fmaxf(o.z, 0.f); o.w = fmaxf(o.w, 0.f);
        } else if constexpr (MODE == 1) {
            float s  = o.x + o.y + o.z + o.w;
            float q2 = o.x * o.x + o.y * o.y + o.z * o.z + o.w * o.w;
#pragma unroll
            for (int m = 32; m; m >>= 1) { s += __shfl_xor(s, m); q2 += __shfl_xor(q2, m); }
            const float mean = s * (1.f / 256.f);
            const float var  = q2 * (1.f / 256.f) - mean * mean;
            const float rstd = rsqrtf(var + LNEPS);
            o.x = (o.x - mean) * rstd * gni.x + bni.x;
            o.y = (o.y - mean) * rstd * gni.y + bni.y;
            o.z = (o.z - mean) * rstd * gni.z + bni.z;
            o.w = (o.w - mean) * rstd * gni.w + bni.w;
        }
        ((float4*)dstL)[((wv << 3) + j) * 64 + lane] = o;
    }
}

// ---------------------------------------------------------------- pass 1
__global__ __launch_bounds__(256, 2) void k_pass1(
    const float* __restrict__ gin, const float* __restrict__ ws_pe,
    const float4* __restrict__ fc1T, const float4* __restrict__ fc2T,
    const float4* __restrict__ vwT, const float* __restrict__ qk2T,
    const float* __restrict__ qb, const float* __restrict__ LNg,
    const float* __restrict__ LNb, const float* __restrict__ nig,
    const float* __restrict__ nib, const float* __restrict__ fc1b,
    const float* __restrict__ fc2b, const float* __restrict__ vb,
    float* __restrict__ attns, float* __restrict__ updp, float* __restrict__ rsp) {
    __shared__ __align__(16) float buf0[32 * 256];
    __shared__ __align__(16) float buf1[32 * 256];
    __shared__ __align__(16) float dotsL[SALL * 36];

    const int tid = threadIdx.x, lane = tid & 63, wv = tid >> 6;
    const int blk = blockIdx.x, bb = blk >> 3, part = blk & 7;
    const int wdx = bb >> 5, bi = bb & 31;
    const int c0 = lane << 2;

    const float4 gln = ld4(LNg + c0), bln = ld4(LNb + c0);
    const float4 gni = ld4(nig + c0), bni = ld4(nib + c0);
    const float4 b1 = ld4(fc1b + c0), b2 = ld4(fc2b + c0), bv = ld4(vb + c0);

    const int islot = tid & 31;
    const int iq = islot < SALL ? islot : SALL - 1;
    const float qbv = qb[iq];
    const int jg = tid >> 5;  // 0..7 (token quad)

    float upd[NAC];
#pragma unroll
    for (int i = 0; i < NAC; ++i) upd[i] = 0.f;
    float rsacc = 0.f;

    for (int tt = part * TPP; tt < part * TPP + TPP; ++tt) {
        const int fo = tt / 6, sp0 = (tt % 6) * 32;
        const float4* src = (const float4*)gin + ((bi * NF + 2 * wdx + fo) * SPF + sp0) * 64;
        const float4* pes = (const float4*)ws_pe + (fo * SPF + sp0) * 64;
        // ---- load + PE + LN(LN) -> buf0 ----
#pragma unroll
        for (int ii = 0; ii < 8; ++ii) {
            float4 a = src[tid + 256 * ii];
            const float4 p = pes[tid + 256 * ii];
            a.x += p.x; a.y += p.y; a.z += p.z; a.w += p.w;
            float s  = a.x + a.y + a.z + a.w;
            float q2 = a.x * a.x + a.y * a.y + a.z * a.z + a.w * a.w;
#pragma unroll
            for (int m = 32; m; m >>= 1) { s += __shfl_xor(s, m); q2 += __shfl_xor(q2, m); }
            const float mean = s * (1.f / 256.f);
            const float var  = q2 * (1.f / 256.f) - mean * mean;
            const float rstd = rsqrtf(var + LNEPS);
            const int j = wv + (ii << 2);  // token owned entirely by this wave
            float4 o;
            o.x = (a.x - mean) * rstd * gln.x + bln.x;
            o.y = (a.y - mean) * rstd * gln.y + bln.y;
            o.z = (a.z - mean) * rstd * gln.z + bln.z;
            o.w = (a.w - mean) * rstd * gln.w + bln.w;
            ((float4*)buf0)[j * 64 + lane] = o;
        }
        __syncthreads();
        gemm_step<0>(buf0, buf1, fc1T, b1, lane, wv, gni, bni);  // FC1 + relu
        __syncthreads();
        gemm_step<1>(buf1, buf0, fc2T, b2, lane, wv, gni, bni);  // FC2 + LN(ni) -> xn
        __syncthreads();
        gemm_step<2>(buf0, buf1, vwT, bv, lane, wv, gni, bni);   // vv
        // ---- dots: (22 x 32) = qk2 . xn  (reads buf0 only; no barrier needed vs G3) ----
        {
            float a0 = qbv, a1 = qbv, a2 = qbv, a3 = qbv;
            const float* x0 = buf0 + (jg * 4) * 256;
            for (int k = 0; k < 256; k += 4) {
                const float q0 = qk2T[(k + 0) * SALL + iq];
                const float q1 = qk2T[(k + 1) * SALL + iq];
                const float q2_ = qk2T[(k + 2) * SALL + iq];
                const float q3 = qk2T[(k + 3) * SALL + iq];
                const float4 x4a = *(const float4*)(x0 + 0 * 256 + k);
                const float4 x4b = *(const float4*)(x0 + 1 * 256 + k);
                const float4 x4c = *(const float4*)(x0 + 2 * 256 + k);
                const float4 x4d = *(const float4*)(x0 + 3 * 256 + k);
                a0 = fmaf(x4a.x, q0, fmaf(x4a.y, q1, fmaf(x4a.z, q2_, fmaf(x4a.w, q3, a0))));
                a1 = fmaf(x4b.x, q0, fmaf(x4b.y, q1, fmaf(x4b.z, q2_, fmaf(x4b.w, q3, a1))));
                a2 = fmaf(x4c.x, q0, fmaf(x4c.y, q1, fmaf(x4c.z, q2_, fmaf(x4c.w, q3, a2))));
                a3 = fmaf(x4d.x, q0, fmaf(x4d.y, q1, fmaf(x4d.z, q2_, fmaf(x4d.w, q3, a3))));
            }
            if (islot < SALL) {
                dotsL[islot * 36 + jg * 4 + 0] = a0 * SCL;
                dotsL[islot * 36 + jg * 4 + 1] = a1 * SCL;
                dotsL[islot * 36 + jg * 4 + 2] = a2 * SCL;
                dotsL[islot * 36 + jg * 4 + 3] = a3 * SCL;
            }
        }
        __syncthreads();
        // ---- softmax over the 22 slots, per token ----
        if (tid < 32) {
            float dv[SALL];
            float mx = -1e30f;
#pragma unroll
            for (int i = 0; i < SALL; ++i) {
                dv[i] = dotsL[i * 36 + tid];
                mx = fmaxf(mx, dv[i]);
            }
            float sum = 0.f;
#pragma unroll
            for (int i = 0; i < SALL; ++i) { dv[i] = __expf(dv[i] - mx); sum += dv[i]; }
            const float inv = 1.f / sum;
#pragma unroll
            for (int i = 0; i < SALL; ++i) dotsL[i * 36 + tid] = dv[i] * inv + EPS;
        }
        __syncthreads();
        // ---- attn_ori out + rowsum + upd accumulation ----
        const int tok0 = tt * 32;
        float* ao = attns + bi * (NWIN * SALL * NTOK) + wdx * (SALL * NTOK) + tok0;
#pragma unroll
        for (int rep = 0; rep < 3; ++rep) {
            const int idx = tid + rep * 256;
            if (idx < SALL * 32) {
                const int i = idx >> 5, j = idx & 31;
                ao[i * NTOK + j] = dotsL[i * 36 + j];
            }
        }
        if (tid < NAC) {
            float s = 0.f;
#pragma unroll
            for (int j = 0; j < 32; ++j) s += dotsL[tid * 36 + j];
            rsacc += s;
        }
        // upd[i][d=tid] += sum_j a[i][j] * vv[j][d]
#pragma unroll
        for (int jq = 0; jq < 8; ++jq) {
            const float v0 = buf1[(jq * 4 + 0) * 256 + tid];
            const float v1 = buf1[(jq * 4 + 1) * 256 + tid];
            const float v2 = buf1[(jq * 4 + 2) * 256 + tid];
            const float v3 = buf1[(jq * 4 + 3) * 256 + tid];
#pragma unroll
            for (int i = 0; i < NAC; ++i) {
                const float4 a = *(const float4*)&dotsL[i * 36 + jq * 4];
                upd[i] = fmaf(a.x, v0, fmaf(a.y, v1, fmaf(a.z, v2, fmaf(a.w, v3, upd[i]))));
            }
        }
        __syncthreads();  // buffers reused next tile
    }
    float* up = updp + blk * (NAC * 256);
#pragma unroll
    for (int i = 0; i < NAC; ++i) up[i * 256 + tid] = upd[i];
    if (tid < NAC) rsp[blk * NAC + tid] = rsacc;
}

// ---------------------------------------------------------------- pass 2: GRU + residual MLP
__global__ __launch_bounds__(256) void k_pass2(
    const float* __restrict__ updp, const float* __restrict__ rsp,
    const float* __restrict__ gwiT, const float* __restrict__ gbi,
    const float* __restrict__ hg0, const float* __restrict__ slots,
    const float* __restrict__ npfg, const float* __restrict__ npfb,
    const float* __restrict__ ff1T, const float* __restrict__ ff1b,
    const float* __restrict__ ff2T, const float* __restrict__ ff2b,
    float* __restrict__ sout) {
    __shared__ float u[256];
    __shared__ float red[8];
    const int t = threadIdx.x, lane = t & 63, wvi = t >> 6;
    const int blk = blockIdx.x, bb = blk >> 2, sg = blk & 3;
    const int wdx = bb >> 5, bi = bb & 31;
    const float* upb = updp + (bb * PARTS) * (NAC * 256);
    const float* rsb = rsp + (bb * PARTS) * NAC;
    for (int m = 0; m < 5; ++m) {
        const int i = sg * 5 + m;
        float rs = 0.f, uv = 0.f;
#pragma unroll
        for (int p = 0; p < PARTS; ++p) {
            rs += rsb[p * NAC + i];
            uv += upb[p * (NAC * 256) + i * 256 + t];
        }
        uv /= rs;
        u[t] = uv;
        __syncthreads();
        float a0 = gbi[t], a1 = gbi[t + 256], a2 = gbi[t + 512];
        for (int k = 0; k < 256; ++k) {
            const float s = u[k];
            a0 = fmaf(s, gwiT[k * 768 + t], a0);
            a1 = fmaf(s, gwiT[k * 768 + t + 256], a1);
            a2 = fmaf(s, gwiT[k * 768 + t + 512], a2);
        }
        const float r = sigm(a0 + hg0[i * 768 + t]);
        const float z = sigm(a1 + hg0[i * 768 + t + 256]);
        const float n = tanhf(a2 + r * hg0[i * 768 + t + 512]);
        const float hp = slots[i * 256 + t];
        const float h = (1.f - z) * n + z * hp;
        // LN(npf)
        float s1 = h, s2 = h * h;
#pragma unroll
        for (int mm = 32; mm; mm >>= 1) { s1 += __shfl_xor(s1, mm); s2 += __shfl_xor(s2, mm); }
        __syncthreads();  // everyone done reading u
        if (lane == 0) { red[wvi] = s1; red[4 + wvi] = s2; }
        __syncthreads();
        const float fs = red[0] + red[1] + red[2] + red[3];
        const float fq = red[4] + red[5] + red[6] + red[7];
        const float mean = fs * (1.f / 256.f);
        const float var  = fq * (1.f / 256.f) - mean * mean;
        const float rstd = rsqrtf(var + LNEPS);
        u[t] = (h - mean) * rstd * npfg[t] + npfb[t];
        __syncthreads();
        float f1 = ff1b[t];
        for (int k = 0; k < 256; ++k) f1 = fmaf(u[k], ff1T[k * 256 + t], f1);
        f1 = fmaxf(f1, 0.f);
        __syncthreads();
        u[t] = f1;
        __syncthreads();
        float f2 = ff2b[t];
        for (int k = 0; k < 256; ++k) f2 = fmaf(u[k], ff2T[k * 256 + t], f2);
        sout[bi * (NWIN * NAC * 256) + wdx * (NAC * 256) + i * 256 + t] = h + f2;
        __syncthreads();
    }
}

// ---------------------------------------------------------------- launcher
extern "C" void kernel_launch(void* const* d_in, const int* in_sizes, int n_in,
                              void* d_out, int out_size, void* d_ws, size_t ws_size,
                              hipStream_t stream) {
    const float* inputs = (const float*)d_in[0];
    const float* slots  = (const float*)d_in[1];
    const float* pe_w   = (const float*)d_in[2];
    const float* pe_b   = (const float*)d_in[3];
    const float* LN_g   = (const float*)d_in[4];
    const float* LN_b   = (const float*)d_in[5];
    const float* ni_g   = (const float*)d_in[6];
    const float* ni_b   = (const float*)d_in[7];
    const float* ns_g   = (const float*)d_in[8];
    const float* ns_b   = (const float*)d_in[9];
    const float* npf_g  = (const float*)d_in[10];
    const float* npf_b  = (const float*)d_in[11];
    const float* FC1_w  = (const float*)d_in[12];
    const float* FC1_b  = (const float*)d_in[13];
    const float* FC2_w  = (const float*)d_in[14];
    const float* FC2_b  = (const float*)d_in[15];
    const float* q_w    = (const float*)d_in[16];
    const float* q_b    = (const float*)d_in[17];
    const float* k_w    = (const float*)d_in[18];
    const float* k_b    = (const float*)d_in[19];
    const float* v_w    = (const float*)d_in[20];
    const float* v_b    = (const float*)d_in[21];
    const float* ff1_w  = (const float*)d_in[22];
    const float* ff1_b  = (const float*)d_in[23];
    const float* ff2_w  = (const float*)d_in[24];
    const float* ff2_b  = (const float*)d_in[25];
    const float* gru_wi = (const float*)d_in[26];
    const float* gru_wh = (const float*)d_in[27];
    const float* gru_bi = (const float*)d_in[28];
    const float* gru_bh = (const float*)d_in[29];

    float* ws    = (float*)d_ws;
    float* out   = (float*)d_out;
    float* attns = out + 32 * 7 * 20 * 256;  // slots_out first, then attns

    TPtrs tp;
    tp.src[0] = FC1_w;  tp.dst[0] = ws + OFF_FC1T; tp.osz[0] = 256;
    tp.src[1] = FC2_w;  tp.dst[1] = ws + OFF_FC2T; tp.osz[1] = 256;
    tp.src[2] = v_w;    tp.dst[2] = ws + OFF_VWT;  tp.osz[2] = 256;
    tp.src[3] = q_w;    tp.dst[3] = ws + OFF_QWT;  tp.osz[3] = 256;
    tp.src[4] = ff1_w;  tp.dst[4] = ws + OFF_FF1T; tp.osz[4] = 256;
    tp.src[5] = ff2_w;  tp.dst[5] = ws + OFF_FF2T; tp.osz[5] = 256;
    tp.src[6] = gru_wi; tp.dst[6] = ws + OFF_GWIT; tp.osz[6] = 768;
    tp.src[7] = gru_wh; tp.dst[7] = ws + OFF_GWHT; tp.osz[7] = 768;

    k_trans<<<768, 256, 0, stream>>>(tp);
    k_pe<<<768, 64, 0, stream>>>(pe_w, pe_b, ws + OFF_PE);
    k_q<<<SALL, 256, 0, stream>>>(slots, ns_g, ns_b, ws + OFF_QWT, q_b, k_b,
                                  ws + OFF_Q, ws + OFF_QB);
    k_qk2<<<SALL, 256, 0, stream>>>(ws + OFF_Q, k_w, ws + OFF_QK2T);
    k_hg<<<SALL, 256, 0, stream>>>(slots, ws + OFF_GWHT, gru_bh, ws + OFF_HG0);
    k_pass1<<<BWIN * PARTS, 256, 0, stream>>>(
        inputs, ws + OFF_PE, (const float4*)(ws + OFF_FC1T),
        (const float4*)(ws + OFF_FC2T), (const float4*)(ws + OFF_VWT),
        ws + OFF_QK2T, ws + OFF_QB, LN_g, LN_b, ni_g, ni_b, FC1_b, FC2_b, v_b,
        attns, ws + OFF_UPDP, ws + OFF_RSP);
    k_pass2<<<BWIN * 4, 256, 0, stream>>>(
        ws + OFF_UPDP, ws + OFF_RSP, ws + OFF_GWIT, gru_bi, ws + OFF_HG0, slots,
        npf_g, npf_b, ws + OFF_FF1T, ff1_b, ws + OFF_FF2T, ff2_b, out);
}